// Round 4
// baseline (1492.827 us; speedup 1.0000x reference)
//
#include <hip/hip_runtime.h>

#define D 128
#define DE 16
#define NL 4
#define EPSV 1e-5f
// K-step counts (K padded to S*32)
#define S_M1 9   // 2D+DE = 272 -> 288
#define S_M2 4   // D = 128
#define S_U1 8   // 2D = 256
#define S_U2 4   // D = 128

using f32x4  = __attribute__((ext_vector_type(4))) float;
using bf16x8 = __attribute__((ext_vector_type(8))) short;

#define MFMA16(a, b, c) __builtin_amdgcn_mfma_f32_16x16x32_bf16((a), (b), (c), 0, 0, 0)

__device__ __forceinline__ unsigned short f2bf(float x) {
  unsigned int u = __float_as_uint(x);
  u = (u + 0x7FFFu + ((u >> 16) & 1u)) >> 16;  // RNE
  return (unsigned short)u;
}

__device__ __forceinline__ bf16x8 pack8(float4 a, float4 b) {
  bf16x8 o;
  o[0] = (short)f2bf(a.x); o[1] = (short)f2bf(a.y);
  o[2] = (short)f2bf(a.z); o[3] = (short)f2bf(a.w);
  o[4] = (short)f2bf(b.x); o[5] = (short)f2bf(b.y);
  o[6] = (short)f2bf(b.z); o[7] = (short)f2bf(b.w);
  return o;
}

// ---------------- prep kernels ----------------
// Fragment-ordered folded weights:
//   out[((l*S + s)*8 + n)*512 + lane*8 + e] = Wfold[k][c],
//   k = s*32 + (lane>>4)*8 + e,  c = n*16 + (lane&15)
// so the GEMM's B-fragment load is a coalesced 16B/lane read.
__global__ void wprep_kernel(const float* __restrict__ W, const float* __restrict__ g,
                             const float* __restrict__ v, unsigned short* __restrict__ out,
                             int K, int S, int total) {
  int idx = blockIdx.x * 256 + threadIdx.x;
  if (idx >= total) return;
  int e  = idx & 7;
  int l0 = (idx >> 3) & 63;
  int f  = idx >> 9;
  int n  = f & 7;
  int sf = f >> 3;
  int s  = sf % S;
  int l  = sf / S;
  int k  = s * 32 + ((l0 >> 4) << 3) + e;
  int c  = (n << 4) + (l0 & 15);
  float val = 0.f;
  if (k < K) {
    float sc = g[l * D + c] * rsqrtf(v[l * D + c] + EPSV);
    val = W[((size_t)(l * K + k)) * D + c] * sc;
  }
  out[idx] = f2bf(val);
}

__global__ void bprep_kernel(const float* __restrict__ b, const float* __restrict__ g,
                             const float* __restrict__ be, const float* __restrict__ m,
                             const float* __restrict__ v, float* __restrict__ out) {
  int idx = blockIdx.x * 256 + threadIdx.x;
  if (idx >= NL * D) return;
  float s = g[idx] * rsqrtf(v[idx] + EPSV);
  out[idx] = (b[idx] - m[idx]) * s + be[idx];
}

__global__ void cvt4_kernel(const float* __restrict__ src, unsigned short* __restrict__ dst, int n4) {
  int idx = blockIdx.x * 256 + threadIdx.x;
  if (idx >= n4) return;
  float4 f = reinterpret_cast<const float4*>(src)[idx];
  unsigned long long p = (unsigned long long)f2bf(f.x)
                       | ((unsigned long long)f2bf(f.y) << 16)
                       | ((unsigned long long)f2bf(f.z) << 32)
                       | ((unsigned long long)f2bf(f.w) << 48);
  reinterpret_cast<unsigned long long*>(dst)[idx] = p;
}

// h = x @ Win + b_in  (f32), also write bf16 copy
__global__ void xproj_kernel(const float* __restrict__ x, const float* __restrict__ Win,
                             const float* __restrict__ bin, float* __restrict__ h,
                             unsigned short* __restrict__ hbf, int N) {
  int t = blockIdx.x * 256 + threadIdx.x;
  int node = t >> 7, c = t & 127;
  if (node >= N) return;
  const float* xr = x + (size_t)node * 64;
  float acc = bin[c];
#pragma unroll
  for (int k = 0; k < 64; ++k) acc = fmaf(xr[k], Win[k * D + c], acc);
  h[t] = acc;
  hbf[t] = f2bf(acc);
}

// ---------------- edge message kernel (barrier-free) ----------------
// per block: 128 edges, 4 independent waves, each wave M=32 x N=128.
// A gathered from global (hoisted); B loaded coalesced from fragment-ordered
// weights (L2-resident); m1 round-trips through per-wave LDS chunk (intra-wave).
__global__ __launch_bounds__(256)
void edge_kernel(const unsigned short* __restrict__ hbf,
                 const unsigned short* __restrict__ ebf,
                 const int* __restrict__ eidx,
                 const unsigned short* __restrict__ W1f,   // frag-ordered [S_M1*8][512]
                 const unsigned short* __restrict__ W2f,   // frag-ordered [S_M2*8][512]
                 const float* __restrict__ b1,
                 const float* __restrict__ b2,
                 float* __restrict__ agg, int E) {
  __shared__ unsigned short m1ls[4][32 * 128];  // 8KB per wave, intra-wave only

  const int tid = threadIdx.x;
  const int wid = tid >> 6;
  const int lane = tid & 63;
  const int g = lane >> 4;
  const int r = lane & 15;
  const int ebase = blockIdx.x * 128;

  const int er0 = ebase + wid * 32 + r;
  const int er1 = er0 + 16;
  const bool ev0 = er0 < E, ev1 = er1 < E;
  const int dst0 = ev0 ? eidx[E + er0] : 0;
  const int src0 = ev0 ? eidx[er0] : 0;
  const int dst1 = ev1 ? eidx[E + er1] : 0;
  const int src1 = ev1 ? eidx[er1] : 0;

  // ---- hoist ALL A fragments (random-latency gathers, 18 x 16B in flight) ----
  bf16x8 aD0[4], aD1[4], aS0[4], aS1[4];
#pragma unroll
  for (int s = 0; s < 4; ++s) {
    aD0[s] = *reinterpret_cast<const bf16x8*>(hbf + (size_t)dst0 * D + s * 32 + g * 8);
    aD1[s] = *reinterpret_cast<const bf16x8*>(hbf + (size_t)dst1 * D + s * 32 + g * 8);
    aS0[s] = *reinterpret_cast<const bf16x8*>(hbf + (size_t)src0 * D + s * 32 + g * 8);
    aS1[s] = *reinterpret_cast<const bf16x8*>(hbf + (size_t)src1 * D + s * 32 + g * 8);
  }
  bf16x8 aE0, aE1;
#pragma unroll
  for (int q = 0; q < 8; ++q) { aE0[q] = 0; aE1[q] = 0; }
  if (g < 2) {
    if (ev0) aE0 = *reinterpret_cast<const bf16x8*>(ebf + (size_t)er0 * DE + g * 8);
    if (ev1) aE1 = *reinterpret_cast<const bf16x8*>(ebf + (size_t)er1 * DE + g * 8);
  }

  float bia1[8], bia2[8];
#pragma unroll
  for (int n = 0; n < 8; ++n) { bia1[n] = b1[n * 16 + r]; bia2[n] = b2[n * 16 + r]; }

  f32x4 acc0[8], acc1[8];
#pragma unroll
  for (int n = 0; n < 8; ++n)
#pragma unroll
    for (int q = 0; q < 4; ++q) { acc0[n][q] = 0.f; acc1[n][q] = 0.f; }

  // ---- GEMM1: 9 K-steps, B coalesced from L2, no barriers ----
#pragma unroll
  for (int s = 0; s < S_M1; ++s) {
    bf16x8 a0 = (s < 4) ? aD0[s & 3] : (s < 8) ? aS0[(s - 4) & 3] : aE0;
    bf16x8 a1 = (s < 4) ? aD1[s & 3] : (s < 8) ? aS1[(s - 4) & 3] : aE1;
#pragma unroll
    for (int n = 0; n < 8; ++n) {
      bf16x8 b = *reinterpret_cast<const bf16x8*>(W1f + (((s * 8 + n) << 9) + (lane << 3)));
      acc0[n] = MFMA16(a0, b, acc0[n]);
      acc1[n] = MFMA16(a1, b, acc1[n]);
    }
  }

  // m1 = relu(acc + bias1) -> bf16 -> per-wave swizzled LDS
  unsigned short* m1w = &m1ls[wid][0];
#pragma unroll
  for (int n = 0; n < 8; ++n)
#pragma unroll
    for (int j = 0; j < 4; ++j) {
      int col = n * 16 + r;
      int row0 = g * 4 + j, row1 = row0 + 16;
      m1w[row0 * 128 + (col ^ ((row0 & 7) << 3))] = f2bf(fmaxf(acc0[n][j] + bia1[n], 0.f));
      m1w[row1 * 128 + (col ^ ((row1 & 7) << 3))] = f2bf(fmaxf(acc1[n][j] + bia1[n], 0.f));
    }

  f32x4 c0[8], c1[8];
#pragma unroll
  for (int n = 0; n < 8; ++n)
#pragma unroll
    for (int q = 0; q < 4; ++q) { c0[n][q] = 0.f; c1[n][q] = 0.f; }

  // ---- GEMM2: 4 K-steps (intra-wave LDS reads, no barriers) ----
#pragma unroll
  for (int s = 0; s < S_M2; ++s) {
    int k0 = s * 32 + g * 8;
    bf16x8 a0 = *reinterpret_cast<const bf16x8*>(m1w + r * 128 + (k0 ^ ((r & 7) << 3)));
    bf16x8 a1 = *reinterpret_cast<const bf16x8*>(m1w + (r + 16) * 128 + (k0 ^ ((r & 7) << 3)));
#pragma unroll
    for (int n = 0; n < 8; ++n) {
      bf16x8 b = *reinterpret_cast<const bf16x8*>(W2f + (((s * 8 + n) << 9) + (lane << 3)));
      c0[n] = MFMA16(a0, b, c0[n]);
      c1[n] = MFMA16(a1, b, c1[n]);
    }
  }

  // epilogue: relu(c + bias2) -> atomic scatter-add into agg[dst]
#pragma unroll
  for (int h2 = 0; h2 < 2; ++h2) {
#pragma unroll
    for (int j = 0; j < 4; ++j) {
      int rloc = g * 4 + j;
      int eg = ebase + wid * 32 + h2 * 16 + rloc;
      int dstv = h2 ? __shfl(dst1, rloc, 64) : __shfl(dst0, rloc, 64);
      if (eg < E) {
        float* ap = agg + (size_t)dstv * D + r;
#pragma unroll
        for (int n = 0; n < 8; ++n) {
          float vv = h2 ? fmaxf(c1[n][j] + bia2[n], 0.f) : fmaxf(c0[n][j] + bia2[n], 0.f);
          unsafeAtomicAdd(ap + n * 16, vv);
        }
      }
    }
  }
}

// ---------------- node update kernel (barrier-free) ----------------
__global__ __launch_bounds__(256)
void node_kernel(const unsigned short* __restrict__ hbf,
                 const float* __restrict__ agg,
                 const unsigned short* __restrict__ W1f,  // frag-ordered [S_U1*8][512]
                 const unsigned short* __restrict__ W2f,  // frag-ordered [S_U2*8][512]
                 const float* __restrict__ b1,
                 const float* __restrict__ b2,
                 float* __restrict__ h,
                 unsigned short* __restrict__ hbfo, int N) {
  __shared__ unsigned short m1ls[4][32 * 128];

  const int tid = threadIdx.x;
  const int wid = tid >> 6;
  const int lane = tid & 63;
  const int g = lane >> 4;
  const int r = lane & 15;
  const int nbase = blockIdx.x * 128;

  const int nr0 = nbase + wid * 32 + r;
  const int nr1 = nr0 + 16;
  const int ar0 = (nr0 < N) ? nr0 : 0;
  const int ar1 = (nr1 < N) ? nr1 : 0;

  // hoist A fragments: h rows + agg rows (packed to bf16)
  bf16x8 aH0[4], aH1[4], aG0[4], aG1[4];
#pragma unroll
  for (int s = 0; s < 4; ++s) {
    aH0[s] = *reinterpret_cast<const bf16x8*>(hbf + (size_t)ar0 * D + s * 32 + g * 8);
    aH1[s] = *reinterpret_cast<const bf16x8*>(hbf + (size_t)ar1 * D + s * 32 + g * 8);
    const float* p0 = agg + (size_t)ar0 * D + s * 32 + g * 8;
    const float* p1 = agg + (size_t)ar1 * D + s * 32 + g * 8;
    aG0[s] = pack8(*reinterpret_cast<const float4*>(p0), *reinterpret_cast<const float4*>(p0 + 4));
    aG1[s] = pack8(*reinterpret_cast<const float4*>(p1), *reinterpret_cast<const float4*>(p1 + 4));
  }

  float bia1[8], bia2[8];
#pragma unroll
  for (int n = 0; n < 8; ++n) { bia1[n] = b1[n * 16 + r]; bia2[n] = b2[n * 16 + r]; }

  f32x4 acc0[8], acc1[8];
#pragma unroll
  for (int n = 0; n < 8; ++n)
#pragma unroll
    for (int q = 0; q < 4; ++q) { acc0[n][q] = 0.f; acc1[n][q] = 0.f; }

  // ---- GEMM1: K=256, 8 steps ----
#pragma unroll
  for (int s = 0; s < S_U1; ++s) {
    bf16x8 a0 = (s < 4) ? aH0[s & 3] : aG0[(s - 4) & 3];
    bf16x8 a1 = (s < 4) ? aH1[s & 3] : aG1[(s - 4) & 3];
#pragma unroll
    for (int n = 0; n < 8; ++n) {
      bf16x8 b = *reinterpret_cast<const bf16x8*>(W1f + (((s * 8 + n) << 9) + (lane << 3)));
      acc0[n] = MFMA16(a0, b, acc0[n]);
      acc1[n] = MFMA16(a1, b, acc1[n]);
    }
  }

  unsigned short* m1w = &m1ls[wid][0];
#pragma unroll
  for (int n = 0; n < 8; ++n)
#pragma unroll
    for (int j = 0; j < 4; ++j) {
      int col = n * 16 + r;
      int row0 = g * 4 + j, row1 = row0 + 16;
      m1w[row0 * 128 + (col ^ ((row0 & 7) << 3))] = f2bf(fmaxf(acc0[n][j] + bia1[n], 0.f));
      m1w[row1 * 128 + (col ^ ((row1 & 7) << 3))] = f2bf(fmaxf(acc1[n][j] + bia1[n], 0.f));
    }

  f32x4 c0[8], c1[8];
#pragma unroll
  for (int n = 0; n < 8; ++n)
#pragma unroll
    for (int q = 0; q < 4; ++q) { c0[n][q] = 0.f; c1[n][q] = 0.f; }

#pragma unroll
  for (int s = 0; s < S_U2; ++s) {
    int k0 = s * 32 + g * 8;
    bf16x8 a0 = *reinterpret_cast<const bf16x8*>(m1w + r * 128 + (k0 ^ ((r & 7) << 3)));
    bf16x8 a1 = *reinterpret_cast<const bf16x8*>(m1w + (r + 16) * 128 + (k0 ^ ((r & 7) << 3)));
#pragma unroll
    for (int n = 0; n < 8; ++n) {
      bf16x8 b = *reinterpret_cast<const bf16x8*>(W2f + (((s * 8 + n) << 9) + (lane << 3)));
      c0[n] = MFMA16(a0, b, c0[n]);
      c1[n] = MFMA16(a1, b, c1[n]);
    }
  }

  // epilogue: h += relu(c + bias2); refresh bf16 h
#pragma unroll
  for (int h2 = 0; h2 < 2; ++h2) {
#pragma unroll
    for (int j = 0; j < 4; ++j) {
      int rowl = wid * 32 + h2 * 16 + g * 4 + j;
      int node = nbase + rowl;
      if (node < N) {
#pragma unroll
        for (int n = 0; n < 8; ++n) {
          int col = n * 16 + r;
          float vv = h2 ? fmaxf(c1[n][j] + bia2[n], 0.f) : fmaxf(c0[n][j] + bia2[n], 0.f);
          float hv = h[(size_t)node * D + col] + vv;
          h[(size_t)node * D + col] = hv;
          hbfo[(size_t)node * D + col] = f2bf(hv);
        }
      }
    }
  }
}

extern "C" void kernel_launch(void* const* d_in, const int* in_sizes, int n_in,
                              void* d_out, int out_size, void* d_ws, size_t ws_size,
                              hipStream_t stream) {
  const float* x     = (const float*)d_in[0];
  const int*   eidx  = (const int*)d_in[1];
  const float* eattr = (const float*)d_in[2];
  const float* Win   = (const float*)d_in[3];
  const float* bin   = (const float*)d_in[4];
  const float* Wm1 = (const float*)d_in[5];  const float* bm1 = (const float*)d_in[6];
  const float* gm1 = (const float*)d_in[7];  const float* bem1 = (const float*)d_in[8];
  const float* mm1 = (const float*)d_in[9];  const float* vm1 = (const float*)d_in[10];
  const float* Wm2 = (const float*)d_in[11]; const float* bm2 = (const float*)d_in[12];
  const float* gm2 = (const float*)d_in[13]; const float* bem2 = (const float*)d_in[14];
  const float* mm2 = (const float*)d_in[15]; const float* vm2 = (const float*)d_in[16];
  const float* Wu1 = (const float*)d_in[17]; const float* bu1 = (const float*)d_in[18];
  const float* gu1 = (const float*)d_in[19]; const float* beu1 = (const float*)d_in[20];
  const float* mu1 = (const float*)d_in[21]; const float* vu1 = (const float*)d_in[22];
  const float* Wu2 = (const float*)d_in[23]; const float* bu2 = (const float*)d_in[24];
  const float* gu2 = (const float*)d_in[25]; const float* beu2 = (const float*)d_in[26];
  const float* mu2 = (const float*)d_in[27]; const float* vu2 = (const float*)d_in[28];

  const int N = in_sizes[0] / 64;
  const int E = in_sizes[1] / 2;
  float* h = (float*)d_out;

  // workspace layout (16B-aligned slabs)
  char* ws = (char*)d_ws;
  size_t off = 0;
  float* agg = (float*)(ws + off);            off += (size_t)N * D * 4;
  unsigned short* hbf  = (unsigned short*)(ws + off); off += (size_t)N * D * 2;
  unsigned short* ebf  = (unsigned short*)(ws + off); off += (size_t)E * DE * 2;
  unsigned short* W1f  = (unsigned short*)(ws + off); off += (size_t)NL * S_M1 * 4096 * 2;
  unsigned short* W2f  = (unsigned short*)(ws + off); off += (size_t)NL * S_M2 * 4096 * 2;
  unsigned short* Wu1f = (unsigned short*)(ws + off); off += (size_t)NL * S_U1 * 4096 * 2;
  unsigned short* Wu2f = (unsigned short*)(ws + off); off += (size_t)NL * S_U2 * 4096 * 2;
  float* bm1f = (float*)(ws + off); off += (size_t)NL * D * 4;
  float* bm2f = (float*)(ws + off); off += (size_t)NL * D * 4;
  float* bu1f = (float*)(ws + off); off += (size_t)NL * D * 4;
  float* bu2f = (float*)(ws + off); off += (size_t)NL * D * 4;
  if (off > ws_size) return;

  // ---- prep: fold BN into fragment-ordered bf16 weights + biases ----
  {
    int t1 = NL * S_M1 * 4096, t2 = NL * S_M2 * 4096, t3 = NL * S_U1 * 4096;
    wprep_kernel<<<(t1 + 255) / 256, 256, 0, stream>>>(Wm1, gm1, vm1, W1f, 2 * D + DE, S_M1, t1);
    wprep_kernel<<<(t2 + 255) / 256, 256, 0, stream>>>(Wm2, gm2, vm2, W2f, D, S_M2, t2);
    wprep_kernel<<<(t3 + 255) / 256, 256, 0, stream>>>(Wu1, gu1, vu1, Wu1f, 2 * D, S_U1, t3);
    wprep_kernel<<<(t2 + 255) / 256, 256, 0, stream>>>(Wu2, gu2, vu2, Wu2f, D, S_U2, t2);
    bprep_kernel<<<2, 256, 0, stream>>>(bm1, gm1, bem1, mm1, vm1, bm1f);
    bprep_kernel<<<2, 256, 0, stream>>>(bm2, gm2, bem2, mm2, vm2, bm2f);
    bprep_kernel<<<2, 256, 0, stream>>>(bu1, gu1, beu1, mu1, vu1, bu1f);
    bprep_kernel<<<2, 256, 0, stream>>>(bu2, gu2, beu2, mu2, vu2, bu2f);
    int n4 = E * DE / 4;
    cvt4_kernel<<<(n4 + 255) / 256, 256, 0, stream>>>(eattr, ebf, n4);
  }

  // ---- input projection ----
  xproj_kernel<<<(N * D + 255) / 256, 256, 0, stream>>>(x, Win, bin, h, hbf, N);

  // ---- layers ----
  const int eblocks = (E + 127) / 128;
  const int nblocks = (N + 127) / 128;
  for (int l = 0; l < NL; ++l) {
    hipMemsetAsync(agg, 0, (size_t)N * D * 4, stream);
    edge_kernel<<<eblocks, 256, 0, stream>>>(hbf, ebf, eidx,
                                             W1f + (size_t)l * S_M1 * 4096,
                                             W2f + (size_t)l * S_M2 * 4096,
                                             bm1f + l * D, bm2f + l * D, agg, E);
    node_kernel<<<nblocks, 256, 0, stream>>>(hbf, agg,
                                             Wu1f + (size_t)l * S_U1 * 4096,
                                             Wu2f + (size_t)l * S_U2 * 4096,
                                             bu1f + l * D, bu2f + l * D, h, hbf, N);
  }
}

// Round 5
// 965.322 us; speedup vs baseline: 1.5465x; 1.5465x over previous
//
#include <hip/hip_runtime.h>

#define D 128
#define DE 16
#define NL 4
#define EPSV 1e-5f
#define S_M1 9   // 2D+DE = 272 -> 288
#define S_M2 4   // D = 128
#define S_U1 8   // 2D = 256
#define S_U2 4   // D = 128
#define TILE 256           // edges per tile (8 waves x 32)
#define NBEDGE 256         // persistent edge blocks (1 per CU)
#define EDGE_LDS 139264    // 72K (W1) + 32K (W2) + 8*4K (m1 halves)

using f32x4  = __attribute__((ext_vector_type(4))) float;
using bf16x8 = __attribute__((ext_vector_type(8))) short;

#define MFMA16(a, b, c) __builtin_amdgcn_mfma_f32_16x16x32_bf16((a), (b), (c), 0, 0, 0)

__device__ __forceinline__ unsigned short f2bf(float x) {
  unsigned int u = __float_as_uint(x);
  u = (u + 0x7FFFu + ((u >> 16) & 1u)) >> 16;  // RNE
  return (unsigned short)u;
}

__device__ __forceinline__ void gload_lds16(const void* gp, void* lp) {
  typedef __attribute__((address_space(1))) unsigned int as1_u32;
  typedef __attribute__((address_space(3))) unsigned int as3_u32;
  __builtin_amdgcn_global_load_lds((as1_u32*)(unsigned long long)gp,
                                   (as3_u32*)(unsigned int)(unsigned long long)lp,
                                   16, 0, 0);
}

__device__ __forceinline__ bf16x8 pack8(float4 a, float4 b) {
  bf16x8 o;
  o[0] = (short)f2bf(a.x); o[1] = (short)f2bf(a.y);
  o[2] = (short)f2bf(a.z); o[3] = (short)f2bf(a.w);
  o[4] = (short)f2bf(b.x); o[5] = (short)f2bf(b.y);
  o[6] = (short)f2bf(b.z); o[7] = (short)f2bf(b.w);
  return o;
}

// ---------------- prep kernels ----------------
// Fragment-ordered folded weights (validated R4):
//   out[((l*S+s)*8+n)*512 + lane*8 + e] = Wfold[k][c],
//   k = s*32 + (lane>>4)*8 + e,  c = n*16 + (lane&15)
__global__ void wprep_kernel(const float* __restrict__ W, const float* __restrict__ g,
                             const float* __restrict__ v, unsigned short* __restrict__ out,
                             int K, int S, int total) {
  int idx = blockIdx.x * 256 + threadIdx.x;
  if (idx >= total) return;
  int e  = idx & 7;
  int l0 = (idx >> 3) & 63;
  int f  = idx >> 9;
  int n  = f & 7;
  int sf = f >> 3;
  int s  = sf % S;
  int l  = sf / S;
  int k  = s * 32 + ((l0 >> 4) << 3) + e;
  int c  = (n << 4) + (l0 & 15);
  float val = 0.f;
  if (k < K) {
    float sc = g[l * D + c] * rsqrtf(v[l * D + c] + EPSV);
    val = W[((size_t)(l * K + k)) * D + c] * sc;
  }
  out[idx] = f2bf(val);
}

__global__ void bprep_kernel(const float* __restrict__ b, const float* __restrict__ g,
                             const float* __restrict__ be, const float* __restrict__ m,
                             const float* __restrict__ v, float* __restrict__ out) {
  int idx = blockIdx.x * 256 + threadIdx.x;
  if (idx >= NL * D) return;
  float s = g[idx] * rsqrtf(v[idx] + EPSV);
  out[idx] = (b[idx] - m[idx]) * s + be[idx];
}

// h = x @ Win + b_in  (f32), also write bf16 copy
__global__ void xproj_kernel(const float* __restrict__ x, const float* __restrict__ Win,
                             const float* __restrict__ bin, float* __restrict__ h,
                             unsigned short* __restrict__ hbf, int N) {
  int t = blockIdx.x * 256 + threadIdx.x;
  int node = t >> 7, c = t & 127;
  if (node >= N) return;
  const float* xr = x + (size_t)node * 64;
  float acc = bin[c];
#pragma unroll
  for (int k = 0; k < 64; ++k) acc = fmaf(xr[k], Win[k * D + c], acc);
  h[t] = acc;
  hbf[t] = f2bf(acc);
}

// ---------------- counting sort of edges by dst (once per launch) ----------------
__global__ void hist_kernel(const int* __restrict__ eidx, int* __restrict__ hist, int E) {
  int e = blockIdx.x * 256 + threadIdx.x;
  if (e < E) atomicAdd(&hist[eidx[E + e]], 1);
}

__global__ void scan1_kernel(const int* __restrict__ hist, int* __restrict__ bsum, int N) {
  __shared__ int sb[256];
  int i = blockIdx.x * 256 + threadIdx.x;
  sb[threadIdx.x] = (i < N) ? hist[i] : 0;
  __syncthreads();
  for (int d = 128; d > 0; d >>= 1) {
    if (threadIdx.x < d) sb[threadIdx.x] += sb[threadIdx.x + d];
    __syncthreads();
  }
  if (threadIdx.x == 0) bsum[blockIdx.x] = sb[0];
}

// single block: exclusive scan of nb (<=256) partials in place
__global__ void scan2_kernel(int* __restrict__ bsum, int nb) {
  __shared__ int sb[2][256];
  int t = threadIdx.x;
  int v = (t < nb) ? bsum[t] : 0;
  int p = 0;
  sb[0][t] = v; __syncthreads();
#pragma unroll
  for (int d = 1; d < 256; d <<= 1) {
    int nv = sb[p][t] + ((t >= d) ? sb[p][t - d] : 0);
    sb[p ^ 1][t] = nv; p ^= 1;
    __syncthreads();
  }
  if (t < nb) bsum[t] = sb[p][t] - v;
}

// hist -> global exclusive scan (cursor), in place
__global__ void scan3_kernel(int* __restrict__ hist, const int* __restrict__ bsum, int N) {
  __shared__ int sb[2][256];
  int i = blockIdx.x * 256 + threadIdx.x, t = threadIdx.x;
  int v = (i < N) ? hist[i] : 0;
  int p = 0;
  sb[0][t] = v; __syncthreads();
#pragma unroll
  for (int d = 1; d < 256; d <<= 1) {
    int nv = sb[p][t] + ((t >= d) ? sb[p][t - d] : 0);
    sb[p ^ 1][t] = nv; p ^= 1;
    __syncthreads();
  }
  if (i < N) hist[i] = sb[p][t] - v + bsum[blockIdx.x];
}

__global__ void scatter_kernel(const int* __restrict__ eidx, int* __restrict__ cursor,
                               int* __restrict__ dstS, int* __restrict__ srcS,
                               int* __restrict__ eidS, int E) {
  int e = blockIdx.x * 256 + threadIdx.x;
  if (e >= E) return;
  int d = eidx[E + e];
  int pos = atomicAdd(&cursor[d], 1);
  dstS[pos] = d;
  srcS[pos] = eidx[e];
  eidS[pos] = e;
}

// permute+convert eattr into sorted bf16 rows
__global__ void eperm_kernel(const float* __restrict__ eattr, const int* __restrict__ eidS,
                             unsigned short* __restrict__ ebfS, int E) {
  int i = blockIdx.x * 256 + threadIdx.x;
  if (i >= E) return;
  const float4* src = reinterpret_cast<const float4*>(eattr + (size_t)eidS[i] * DE);
  bf16x8 a = pack8(src[0], src[1]);
  bf16x8 b = pack8(src[2], src[3]);
  *reinterpret_cast<bf16x8*>(ebfS + (size_t)i * DE) = a;
  *reinterpret_cast<bf16x8*>(ebfS + (size_t)i * DE + 8) = b;
}

// ---------------- edge message kernel ----------------
// persistent blocks (1/CU), 512 thr = 8 waves, weights in LDS once,
// dst-sorted edges, barrier-free tile loop, run-compressed atomics.
__global__ __launch_bounds__(512, 2)
void edge_kernel(const unsigned short* __restrict__ hbf,
                 const unsigned short* __restrict__ ebfS,
                 const int* __restrict__ dstS,
                 const int* __restrict__ srcS,
                 const unsigned short* __restrict__ W1f,   // frag-ordered, 72KB
                 const unsigned short* __restrict__ W2f,   // frag-ordered, 32KB
                 const float* __restrict__ b1,
                 const float* __restrict__ b2,
                 float* __restrict__ agg, int E) {
  extern __shared__ char smem[];
  const int tid = threadIdx.x;
  const int wid = tid >> 6, lane = tid & 63, g = lane >> 4, r = lane & 15;
  unsigned short* Wls = (unsigned short*)smem;  // W1 shorts [0,36864), W2 [36864,53248)
  unsigned short* m1w = (unsigned short*)(smem + 106496 + (wid << 12));  // 4KB/wave half-buffer

  // ---- one-time weight stage: 13*512 x 16B = 104KB ----
#pragma unroll
  for (int i = 0; i < 13; ++i) {
    if (i < 9) gload_lds16(W1f + ((i * 512 + tid) << 3), smem + ((i * 512 + tid) << 4));
    else       gload_lds16(W2f + (((i - 9) * 512 + tid) << 3), smem + 73728 + (((i - 9) * 512 + tid) << 4));
  }

  float bia1[8], bia2[8];
#pragma unroll
  for (int n = 0; n < 8; ++n) { bia1[n] = b1[n * 16 + r]; bia2[n] = b2[n * 16 + r]; }

  const int T = (E + TILE - 1) / TILE;
  const int tpb = (T + gridDim.x - 1) / gridDim.x;
  const int t0 = blockIdx.x * tpb;          // chunked: block owns contiguous dst range
  const int t1 = min(T, t0 + tpb);

  __syncthreads();

  for (int t = t0; t < t1; ++t) {
    const int i0 = t * TILE + wid * 32 + r;
    const int i1 = i0 + 16;
    const int ii0 = min(i0, E - 1), ii1 = min(i1, E - 1);
    const int dst0 = dstS[ii0], src0 = srcS[ii0];
    const int dst1 = dstS[ii1], src1 = srcS[ii1];

    // gathers: dst rows nearly-uniform (sorted), src random
    bf16x8 aD0[4], aD1[4], aS0[4], aS1[4];
#pragma unroll
    for (int s = 0; s < 4; ++s) {
      aD0[s] = *reinterpret_cast<const bf16x8*>(hbf + (size_t)dst0 * D + s * 32 + g * 8);
      aD1[s] = *reinterpret_cast<const bf16x8*>(hbf + (size_t)dst1 * D + s * 32 + g * 8);
      aS0[s] = *reinterpret_cast<const bf16x8*>(hbf + (size_t)src0 * D + s * 32 + g * 8);
      aS1[s] = *reinterpret_cast<const bf16x8*>(hbf + (size_t)src1 * D + s * 32 + g * 8);
    }
    bf16x8 aE0, aE1;
#pragma unroll
    for (int q = 0; q < 8; ++q) { aE0[q] = 0; aE1[q] = 0; }
    if (g < 2) {
      aE0 = *reinterpret_cast<const bf16x8*>(ebfS + (size_t)ii0 * DE + g * 8);
      aE1 = *reinterpret_cast<const bf16x8*>(ebfS + (size_t)ii1 * DE + g * 8);
    }

    f32x4 acc0[8], acc1[8];
#pragma unroll
    for (int n = 0; n < 8; ++n)
#pragma unroll
      for (int q = 0; q < 4; ++q) { acc0[n][q] = 0.f; acc1[n][q] = 0.f; }

    // ---- GEMM1: 9 K-steps, B from LDS (staged once) ----
#pragma unroll
    for (int s = 0; s < S_M1; ++s) {
      bf16x8 a0 = (s < 4) ? aD0[s & 3] : (s < 8) ? aS0[(s - 4) & 3] : aE0;
      bf16x8 a1 = (s < 4) ? aD1[s & 3] : (s < 8) ? aS1[(s - 4) & 3] : aE1;
#pragma unroll
      for (int n = 0; n < 8; ++n) {
        bf16x8 b = *reinterpret_cast<const bf16x8*>(Wls + ((s * 8 + n) << 9) + (lane << 3));
        acc0[n] = MFMA16(a0, b, acc0[n]);
        acc1[n] = MFMA16(a1, b, acc1[n]);
      }
    }

    f32x4 c0[8], c1[8];
#pragma unroll
    for (int n = 0; n < 8; ++n)
#pragma unroll
      for (int q = 0; q < 4; ++q) { c0[n][q] = 0.f; c1[n][q] = 0.f; }

    // ---- m1 in two 64-col halves (wave-private LDS, no barriers) + GEMM2 ----
#pragma unroll
    for (int hh = 0; hh < 2; ++hh) {
#pragma unroll
      for (int n4 = 0; n4 < 4; ++n4) {
        int n = hh * 4 + n4;
        int grw = n4 * 2 + (r >> 3);  // 16B granule of col' = n4*16+r
#pragma unroll
        for (int j = 0; j < 4; ++j) {
          int row0 = g * 4 + j, row1 = row0 + 16;
          m1w[(row0 << 6) + ((grw ^ (row0 & 7)) << 3) + (r & 7)] =
              f2bf(fmaxf(acc0[n][j] + bia1[n], 0.f));
          m1w[(row1 << 6) + ((grw ^ (row1 & 7)) << 3) + (r & 7)] =
              f2bf(fmaxf(acc1[n][j] + bia1[n], 0.f));
        }
      }
#pragma unroll
      for (int s2 = 0; s2 < 2; ++s2) {
        int s = hh * 2 + s2;
        int grr = s2 * 4 + g;  // granule of col' = s2*32+g*8
        bf16x8 a0 = *reinterpret_cast<const bf16x8*>(m1w + (r << 6) + ((grr ^ (r & 7)) << 3));
        bf16x8 a1 = *reinterpret_cast<const bf16x8*>(m1w + ((r + 16) << 6) + ((grr ^ ((r + 16) & 7)) << 3));
#pragma unroll
        for (int n = 0; n < 8; ++n) {
          bf16x8 b = *reinterpret_cast<const bf16x8*>(Wls + 36864 + ((s * 8 + n) << 9) + (lane << 3));
          c0[n] = MFMA16(a0, b, c0[n]);
          c1[n] = MFMA16(a1, b, c1[n]);
        }
      }
    }

    // ---- epilogue: bias+relu, run-compress same-dst rows, atomic scatter ----
    int dm0[4], dm1[4];
#pragma unroll
    for (int j = 0; j < 4; ++j) {
      dm0[j] = __shfl(dst0, g * 4 + j, 64);
      dm1[j] = __shfl(dst1, g * 4 + j, 64);
    }
#pragma unroll
    for (int h2 = 0; h2 < 2; ++h2) {
#pragma unroll
      for (int n = 0; n < 8; ++n) {
        float run = 0.f; int dcur = -1;
#pragma unroll
        for (int j = 0; j < 4; ++j) {
          int eg = t * TILE + wid * 32 + h2 * 16 + g * 4 + j;
          int dj = h2 ? dm1[j] : dm0[j];
          float vv = fmaxf((h2 ? c1[n][j] : c0[n][j]) + bia2[n], 0.f);
          if (eg < E) {
            if (dj != dcur) {
              if (dcur >= 0) unsafeAtomicAdd(agg + (size_t)dcur * D + n * 16 + r, run);
              dcur = dj; run = 0.f;
            }
            run += vv;
          }
        }
        if (dcur >= 0) unsafeAtomicAdd(agg + (size_t)dcur * D + n * 16 + r, run);
      }
    }
  }
}

// ---------------- node update kernel (unchanged, validated R4) ----------------
__global__ __launch_bounds__(256)
void node_kernel(const unsigned short* __restrict__ hbf,
                 const float* __restrict__ agg,
                 const unsigned short* __restrict__ W1f,
                 const unsigned short* __restrict__ W2f,
                 const float* __restrict__ b1,
                 const float* __restrict__ b2,
                 float* __restrict__ h,
                 unsigned short* __restrict__ hbfo, int N) {
  __shared__ unsigned short m1ls[4][32 * 128];

  const int tid = threadIdx.x;
  const int wid = tid >> 6;
  const int lane = tid & 63;
  const int g = lane >> 4;
  const int r = lane & 15;
  const int nbase = blockIdx.x * 128;

  const int nr0 = nbase + wid * 32 + r;
  const int nr1 = nr0 + 16;
  const int ar0 = (nr0 < N) ? nr0 : 0;
  const int ar1 = (nr1 < N) ? nr1 : 0;

  bf16x8 aH0[4], aH1[4], aG0[4], aG1[4];
#pragma unroll
  for (int s = 0; s < 4; ++s) {
    aH0[s] = *reinterpret_cast<const bf16x8*>(hbf + (size_t)ar0 * D + s * 32 + g * 8);
    aH1[s] = *reinterpret_cast<const bf16x8*>(hbf + (size_t)ar1 * D + s * 32 + g * 8);
    const float* p0 = agg + (size_t)ar0 * D + s * 32 + g * 8;
    const float* p1 = agg + (size_t)ar1 * D + s * 32 + g * 8;
    aG0[s] = pack8(*reinterpret_cast<const float4*>(p0), *reinterpret_cast<const float4*>(p0 + 4));
    aG1[s] = pack8(*reinterpret_cast<const float4*>(p1), *reinterpret_cast<const float4*>(p1 + 4));
  }

  float bia1[8], bia2[8];
#pragma unroll
  for (int n = 0; n < 8; ++n) { bia1[n] = b1[n * 16 + r]; bia2[n] = b2[n * 16 + r]; }

  f32x4 acc0[8], acc1[8];
#pragma unroll
  for (int n = 0; n < 8; ++n)
#pragma unroll
    for (int q = 0; q < 4; ++q) { acc0[n][q] = 0.f; acc1[n][q] = 0.f; }

#pragma unroll
  for (int s = 0; s < S_U1; ++s) {
    bf16x8 a0 = (s < 4) ? aH0[s & 3] : aG0[(s - 4) & 3];
    bf16x8 a1 = (s < 4) ? aH1[s & 3] : aG1[(s - 4) & 3];
#pragma unroll
    for (int n = 0; n < 8; ++n) {
      bf16x8 b = *reinterpret_cast<const bf16x8*>(W1f + (((s * 8 + n) << 9) + (lane << 3)));
      acc0[n] = MFMA16(a0, b, acc0[n]);
      acc1[n] = MFMA16(a1, b, acc1[n]);
    }
  }

  unsigned short* m1w = &m1ls[wid][0];
#pragma unroll
  for (int n = 0; n < 8; ++n)
#pragma unroll
    for (int j = 0; j < 4; ++j) {
      int col = n * 16 + r;
      int row0 = g * 4 + j, row1 = row0 + 16;
      m1w[row0 * 128 + (col ^ ((row0 & 7) << 3))] = f2bf(fmaxf(acc0[n][j] + bia1[n], 0.f));
      m1w[row1 * 128 + (col ^ ((row1 & 7) << 3))] = f2bf(fmaxf(acc1[n][j] + bia1[n], 0.f));
    }

  f32x4 c0[8], c1[8];
#pragma unroll
  for (int n = 0; n < 8; ++n)
#pragma unroll
    for (int q = 0; q < 4; ++q) { c0[n][q] = 0.f; c1[n][q] = 0.f; }

#pragma unroll
  for (int s = 0; s < S_U2; ++s) {
    int k0 = s * 32 + g * 8;
    bf16x8 a0 = *reinterpret_cast<const bf16x8*>(m1w + r * 128 + (k0 ^ ((r & 7) << 3)));
    bf16x8 a1 = *reinterpret_cast<const bf16x8*>(m1w + (r + 16) * 128 + (k0 ^ ((r & 7) << 3)));
#pragma unroll
    for (int n = 0; n < 8; ++n) {
      bf16x8 b = *reinterpret_cast<const bf16x8*>(W2f + (((s * 8 + n) << 9) + (lane << 3)));
      c0[n] = MFMA16(a0, b, c0[n]);
      c1[n] = MFMA16(a1, b, c1[n]);
    }
  }

#pragma unroll
  for (int h2 = 0; h2 < 2; ++h2) {
#pragma unroll
    for (int j = 0; j < 4; ++j) {
      int rowl = wid * 32 + h2 * 16 + g * 4 + j;
      int node = nbase + rowl;
      if (node < N) {
#pragma unroll
        for (int n = 0; n < 8; ++n) {
          int col = n * 16 + r;
          float vv = h2 ? fmaxf(c1[n][j] + bia2[n], 0.f) : fmaxf(c0[n][j] + bia2[n], 0.f);
          float hv = h[(size_t)node * D + col] + vv;
          h[(size_t)node * D + col] = hv;
          hbfo[(size_t)node * D + col] = f2bf(hv);
        }
      }
    }
  }
}

extern "C" void kernel_launch(void* const* d_in, const int* in_sizes, int n_in,
                              void* d_out, int out_size, void* d_ws, size_t ws_size,
                              hipStream_t stream) {
  const float* x     = (const float*)d_in[0];
  const int*   eidx  = (const int*)d_in[1];
  const float* eattr = (const float*)d_in[2];
  const float* Win   = (const float*)d_in[3];
  const float* bin   = (const float*)d_in[4];
  const float* Wm1 = (const float*)d_in[5];  const float* bm1 = (const float*)d_in[6];
  const float* gm1 = (const float*)d_in[7];  const float* bem1 = (const float*)d_in[8];
  const float* mm1 = (const float*)d_in[9];  const float* vm1 = (const float*)d_in[10];
  const float* Wm2 = (const float*)d_in[11]; const float* bm2 = (const float*)d_in[12];
  const float* gm2 = (const float*)d_in[13]; const float* bem2 = (const float*)d_in[14];
  const float* mm2 = (const float*)d_in[15]; const float* vm2 = (const float*)d_in[16];
  const float* Wu1 = (const float*)d_in[17]; const float* bu1 = (const float*)d_in[18];
  const float* gu1 = (const float*)d_in[19]; const float* beu1 = (const float*)d_in[20];
  const float* mu1 = (const float*)d_in[21]; const float* vu1 = (const float*)d_in[22];
  const float* Wu2 = (const float*)d_in[23]; const float* bu2 = (const float*)d_in[24];
  const float* gu2 = (const float*)d_in[25]; const float* beu2 = (const float*)d_in[26];
  const float* mu2 = (const float*)d_in[27]; const float* vu2 = (const float*)d_in[28];

  const int N = in_sizes[0] / 64;
  const int E = in_sizes[1] / 2;
  float* h = (float*)d_out;

  // workspace layout (16B-aligned slabs), ~62 MB total
  char* ws = (char*)d_ws;
  size_t off = 0;
  float* agg = (float*)(ws + off);                     off += (size_t)N * D * 4;
  unsigned short* hbf  = (unsigned short*)(ws + off);  off += (size_t)N * D * 2;
  unsigned short* ebfS = (unsigned short*)(ws + off);  off += (size_t)E * DE * 2;
  int* dstS = (int*)(ws + off);                        off += (size_t)E * 4;
  int* srcS = (int*)(ws + off);                        off += (size_t)E * 4;
  int* eidS = (int*)(ws + off);                        off += (size_t)E * 4;
  int* hist = (int*)(ws + off);                        off += ((size_t)N * 4 + 15) & ~15ull;
  int* bsum = (int*)(ws + off);                        off += 1024;
  unsigned short* W1f  = (unsigned short*)(ws + off);  off += (size_t)NL * S_M1 * 4096 * 2;
  unsigned short* W2f  = (unsigned short*)(ws + off);  off += (size_t)NL * S_M2 * 4096 * 2;
  unsigned short* Wu1f = (unsigned short*)(ws + off);  off += (size_t)NL * S_U1 * 4096 * 2;
  unsigned short* Wu2f = (unsigned short*)(ws + off);  off += (size_t)NL * S_U2 * 4096 * 2;
  float* bm1f = (float*)(ws + off); off += (size_t)NL * D * 4;
  float* bm2f = (float*)(ws + off); off += (size_t)NL * D * 4;
  float* bu1f = (float*)(ws + off); off += (size_t)NL * D * 4;
  float* bu2f = (float*)(ws + off); off += (size_t)NL * D * 4;
  if (off > ws_size) return;

  hipFuncSetAttribute(reinterpret_cast<const void*>(edge_kernel),
                      hipFuncAttributeMaxDynamicSharedMemorySize, EDGE_LDS);

  // ---- prep: folded frag-ordered weights + biases ----
  {
    int t1 = NL * S_M1 * 4096, t2 = NL * S_M2 * 4096, t3 = NL * S_U1 * 4096;
    wprep_kernel<<<(t1 + 255) / 256, 256, 0, stream>>>(Wm1, gm1, vm1, W1f, 2 * D + DE, S_M1, t1);
    wprep_kernel<<<(t2 + 255) / 256, 256, 0, stream>>>(Wm2, gm2, vm2, W2f, D, S_M2, t2);
    wprep_kernel<<<(t3 + 255) / 256, 256, 0, stream>>>(Wu1, gu1, vu1, Wu1f, 2 * D, S_U1, t3);
    wprep_kernel<<<(t2 + 255) / 256, 256, 0, stream>>>(Wu2, gu2, vu2, Wu2f, D, S_U2, t2);
    bprep_kernel<<<2, 256, 0, stream>>>(bm1, gm1, bem1, mm1, vm1, bm1f);
    bprep_kernel<<<2, 256, 0, stream>>>(bm2, gm2, bem2, mm2, vm2, bm2f);
    bprep_kernel<<<2, 256, 0, stream>>>(bu1, gu1, beu1, mu1, vu1, bu1f);
    bprep_kernel<<<2, 256, 0, stream>>>(bu2, gu2, beu2, mu2, vu2, bu2f);
  }

  // ---- counting sort of edges by dst (edge_index is layer-invariant) ----
  {
    const int NB_H = (N + 255) / 256;   // 196 <= 256
    hipMemsetAsync(hist, 0, (size_t)N * 4, stream);
    hist_kernel<<<(E + 255) / 256, 256, 0, stream>>>(eidx, hist, E);
    scan1_kernel<<<NB_H, 256, 0, stream>>>(hist, bsum, N);
    scan2_kernel<<<1, 256, 0, stream>>>(bsum, NB_H);
    scan3_kernel<<<NB_H, 256, 0, stream>>>(hist, bsum, N);
    scatter_kernel<<<(E + 255) / 256, 256, 0, stream>>>(eidx, hist, dstS, srcS, eidS, E);
    eperm_kernel<<<(E + 255) / 256, 256, 0, stream>>>(eattr, eidS, ebfS, E);
  }

  // ---- input projection ----
  xproj_kernel<<<(N * D + 255) / 256, 256, 0, stream>>>(x, Win, bin, h, hbf, N);

  // ---- layers ----
  const int nblocks = (N + 127) / 128;
  for (int l = 0; l < NL; ++l) {
    hipMemsetAsync(agg, 0, (size_t)N * D * 4, stream);
    edge_kernel<<<NBEDGE, 512, EDGE_LDS, stream>>>(hbf, ebfS, dstS, srcS,
                                                   W1f + (size_t)l * S_M1 * 4096,
                                                   W2f + (size_t)l * S_M2 * 4096,
                                                   bm1f + l * D, bm2f + l * D, agg, E);
    node_kernel<<<nblocks, 256, 0, stream>>>(hbf, agg,
                                             Wu1f + (size_t)l * S_U1 * 4096,
                                             Wu2f + (size_t)l * S_U2 * 4096,
                                             bu1f + l * D, bu2f + l * D, h, hbf, N);
  }
}